// Round 1
// baseline (267.600 us; speedup 1.0000x reference)
//
#include <hip/hip_runtime.h>
#include <math.h>

#define AFWD 0.999f
#define EPS  1e-5f

constexpr int B  = 32;
constexpr int HW = 64 * 64;          // 4096 spatial positions per sample
constexpr int C  = 256;              // channels
constexpr int CQ = C / 4;            // 64 channel-quads (float4)
constexpr int CHUNKS = 32;           // spatial chunks per sample for partial sums
constexpr int ROWS_PER_CHUNK = HW / CHUNKS;  // 128

// ---------------------------------------------------------------------------
// Kernel 1: partial sums per (t, chunk, channel).
// Block = 256 threads: cq = tid&63 (channel quad), rs = tid>>6 (row sub-lane).
// Each thread accumulates float4 sum / sumsq over 32 rows, then LDS-reduce the
// 4 row sub-lanes. Loads are float4, fully coalesced (64 lanes x 16B = 1KB).
// ---------------------------------------------------------------------------
__global__ void k_partial(const float4* __restrict__ x4,
                          float4* __restrict__ psum,
                          float4* __restrict__ psq) {
    const int chunk = blockIdx.x;
    const int t     = blockIdx.y;
    const int tid   = threadIdx.x;
    const int cq    = tid & 63;
    const int rs    = tid >> 6;  // 0..3

    float4 s = make_float4(0.f, 0.f, 0.f, 0.f);
    float4 q = make_float4(0.f, 0.f, 0.f, 0.f);

    const int base_row = t * HW + chunk * ROWS_PER_CHUNK;
    #pragma unroll 4
    for (int k = 0; k < ROWS_PER_CHUNK / 4; ++k) {
        const int r = base_row + rs + k * 4;
        const float4 v = x4[(long)r * CQ + cq];
        s.x += v.x; s.y += v.y; s.z += v.z; s.w += v.w;
        q.x += v.x * v.x; q.y += v.y * v.y; q.z += v.z * v.z; q.w += v.w * v.w;
    }

    __shared__ float4 ls[256];
    __shared__ float4 lq[256];
    ls[tid] = s;
    lq[tid] = q;
    __syncthreads();

    if (tid < 64) {
        float4 a0 = ls[tid], a1 = ls[tid + 64], a2 = ls[tid + 128], a3 = ls[tid + 192];
        float4 b0 = lq[tid], b1 = lq[tid + 64], b2 = lq[tid + 128], b3 = lq[tid + 192];
        float4 ts, tq;
        ts.x = a0.x + a1.x + a2.x + a3.x;
        ts.y = a0.y + a1.y + a2.y + a3.y;
        ts.z = a0.z + a1.z + a2.z + a3.z;
        ts.w = a0.w + a1.w + a2.w + a3.w;
        tq.x = b0.x + b1.x + b2.x + b3.x;
        tq.y = b0.y + b1.y + b2.y + b3.y;
        tq.z = b0.z + b1.z + b2.z + b3.z;
        tq.w = b0.w + b1.w + b2.w + b3.w;
        const int o = (t * CHUNKS + chunk) * CQ + tid;
        psum[o] = ts;
        psq[o]  = tq;
    }
}

// ---------------------------------------------------------------------------
// Kernel 2a: fold chunks -> per-(t,c) mean and biased var. Grid = (B), 256 thr.
// ---------------------------------------------------------------------------
__global__ void k_reduce(const float* __restrict__ psum,
                         const float* __restrict__ psq,
                         float* __restrict__ mean_t,
                         float* __restrict__ var_t) {
    const int t = blockIdx.x;
    const int c = threadIdx.x;
    float s = 0.f, q = 0.f;
    #pragma unroll
    for (int ch = 0; ch < CHUNKS; ++ch) {
        s += psum[(t * CHUNKS + ch) * C + c];
        q += psq [(t * CHUNKS + ch) * C + c];
    }
    const float inv = 1.0f / (float)HW;
    const float m = s * inv;
    mean_t[t * C + c] = m;
    var_t [t * C + c] = q * inv - m * m;
}

// ---------------------------------------------------------------------------
// Kernel 2b: the 32-step EMA scan per channel. 1 block, 256 threads.
// Stores the PRE-update carry (mu_{t-1}, rstd_{t-1}) used to normalize x_t.
// ---------------------------------------------------------------------------
__global__ void k_scan(const float* __restrict__ mu0,
                       const float* __restrict__ var0,
                       const float* __restrict__ mean_t,
                       const float* __restrict__ var_t,
                       float* __restrict__ mu_prev,
                       float* __restrict__ rstd) {
    const int c = threadIdx.x;
    float mu  = mu0[c];
    float var = var0[c];
    #pragma unroll
    for (int t = 0; t < B; ++t) {
        mu_prev[t * C + c] = mu;
        rstd  [t * C + c] = 1.0f / sqrtf(var + EPS);
        const float m  = mean_t[t * C + c];
        const float vt = var_t [t * C + c];
        const float d  = m - mu;
        var = AFWD * var + (1.0f - AFWD) * vt + AFWD * (1.0f - AFWD) * d * d;
        mu  = mu + (1.0f - AFWD) * d;
    }
}

// ---------------------------------------------------------------------------
// Kernel 4: normalize. Grid = (64 chunks, B). 256 threads, 16 float4 each.
// Channel quad per thread is constant (tid&63) since all strides are %64==0,
// so mu/rstd are loaded once per thread.
// ---------------------------------------------------------------------------
__global__ void k_norm(const float4* __restrict__ x4,
                       const float4* __restrict__ mu_prev4,
                       const float4* __restrict__ rstd4,
                       float4* __restrict__ out4) {
    const int t   = blockIdx.y;
    const int tid = threadIdx.x;
    const int cq  = tid & 63;

    const float4 mu = mu_prev4[t * CQ + cq];
    const float4 rs = rstd4  [t * CQ + cq];

    const long base = (long)t * (HW * CQ) + (long)blockIdx.x * (256 * 16);
    #pragma unroll 4
    for (int k = 0; k < 16; ++k) {
        const long i = base + k * 256 + tid;
        const float4 v = x4[i];
        float4 o;
        o.x = (v.x - mu.x) * rs.x;
        o.y = (v.y - mu.y) * rs.y;
        o.z = (v.z - mu.z) * rs.z;
        o.w = (v.w - mu.w) * rs.w;
        out4[i] = o;
    }
}

// ---------------------------------------------------------------------------
// Host launcher.
// Workspace layout (bytes):
//   [0, 1MB)            psum   : float4[B*CHUNKS*CQ]  = 65536 float4
//   [1MB, 2MB)          psq    : float4[B*CHUNKS*CQ]
//   [2MB, +32KB)        mean_t : float[B*C] = 8192
//   [+32KB, +64KB)      var_t  : float[B*C]
//   [+64KB, +96KB)      mu_prev: float[B*C]
//   [+96KB, +128KB)     rstd   : float[B*C]
// Total: 2MB + 128KB.
// ---------------------------------------------------------------------------
extern "C" void kernel_launch(void* const* d_in, const int* in_sizes, int n_in,
                              void* d_out, int out_size, void* d_ws, size_t ws_size,
                              hipStream_t stream) {
    const float* x   = (const float*)d_in[0];
    const float* mu0 = (const float*)d_in[1];
    const float* var0= (const float*)d_in[2];
    // d_in[3] (u0), d_in[4] (v0) are backward-only controls; unused in fwd.

    float* out = (float*)d_out;

    char* ws = (char*)d_ws;
    float4* psum    = (float4*)(ws);
    float4* psq     = (float4*)(ws + (1u << 20));
    float*  mean_t  = (float*) (ws + (2u << 20));
    float*  var_t   = (float*) (ws + (2u << 20) + (32u << 10));
    float*  mu_prev = (float*) (ws + (2u << 20) + (64u << 10));
    float*  rstd    = (float*) (ws + (2u << 20) + (96u << 10));

    const float4* x4 = (const float4*)x;

    // 1) Partial sums over spatial chunks.
    k_partial<<<dim3(CHUNKS, B), 256, 0, stream>>>(x4, psum, psq);

    // 2a) Fold chunks -> mean/var per (t, c).
    k_reduce<<<dim3(B), 256, 0, stream>>>((const float*)psum, (const float*)psq,
                                          mean_t, var_t);

    // 2b) Sequential EMA scan (tiny).
    k_scan<<<dim3(1), 256, 0, stream>>>(mu0, var0, mean_t, var_t, mu_prev, rstd);

    // 3) Normalize.
    k_norm<<<dim3(HW * CQ / (256 * 16), B), 256, 0, stream>>>(
        x4, (const float4*)mu_prev, (const float4*)rstd, (float4*)out);
}

// Round 3
// 261.258 us; speedup vs baseline: 1.0243x; 1.0243x over previous
//
#include <hip/hip_runtime.h>
#include <math.h>

#define AFWD 0.999f
#define EPS  1e-5f

constexpr int B  = 32;
constexpr int HW = 64 * 64;      // 4096 spatial positions per sample
constexpr int C  = 256;          // channels
constexpr int CQ = C / 4;        // 64 channel-quads (float4)
constexpr int CHUNKS = 32;       // spatial chunks per sample
constexpr int RPC = HW / CHUNKS; // 128 rows per chunk

// ---------------------------------------------------------------------------
// Kernel 1: per-(t,chunk) partial sums -> atomicAdd into accum_s/accum_q[t][c].
// Block 256 thr: cq = tid&63 (channel quad), rs = tid>>6 (row sub-lane).
// Wave reads 64 consecutive float4 = 1KB, fully coalesced.
// ---------------------------------------------------------------------------
__global__ void __launch_bounds__(256)
k1_partial(const float4* __restrict__ x4,
           float* __restrict__ accum_s,
           float* __restrict__ accum_q) {
    const int blk   = blockIdx.x;
    const int t     = blk >> 5;
    const int chunk = blk & 31;
    const int tid   = threadIdx.x;
    const int cq    = tid & 63;
    const int rs    = tid >> 6;

    const long base = (long)(t * HW + chunk * RPC) * CQ;

    float4 s = make_float4(0.f, 0.f, 0.f, 0.f);
    float4 q = make_float4(0.f, 0.f, 0.f, 0.f);
    #pragma unroll 4
    for (int k = 0; k < RPC / 4; ++k) {
        const float4 v = x4[base + (long)(rs + k * 4) * CQ + cq];
        s.x += v.x; s.y += v.y; s.z += v.z; s.w += v.w;
        q.x += v.x * v.x; q.y += v.y * v.y; q.z += v.z * v.z; q.w += v.w * v.w;
    }

    __shared__ float4 ls[256];
    __shared__ float4 lq[256];
    ls[tid] = s;
    lq[tid] = q;
    __syncthreads();

    // Thread tid owns channel c = tid. Word index read = k*256 + c -> bank c%32,
    // conflict-free.
    const int c    = tid;
    const int cq2  = c >> 2;
    const int comp = c & 3;
    float ssum = 0.f, qsum = 0.f;
    #pragma unroll
    for (int k = 0; k < 4; ++k) {
        ssum += ((const float*)&ls[k * 64 + cq2])[comp];
        qsum += ((const float*)&lq[k * 64 + cq2])[comp];
    }
    atomicAdd(&accum_s[t * C + c], ssum);
    atomicAdd(&accum_q[t * C + c], qsum);
}

// ---------------------------------------------------------------------------
// Kernel 2: per-block redundant EMA scan (<=31 steps from finalized accum),
// then normalize this block's chunk. No cross-block ordering assumptions:
// the kernel boundary after k1 is the only sync.
// ---------------------------------------------------------------------------
__global__ void __launch_bounds__(256)
k2_norm(const float4* __restrict__ x4,
        const float* __restrict__ mu0,
        const float* __restrict__ var0,
        const float* __restrict__ accum_s,
        const float* __restrict__ accum_q,
        float4* __restrict__ out4) {
    const int blk   = blockIdx.x;
    const int t     = blk >> 5;
    const int chunk = blk & 31;
    const int tid   = threadIdx.x;

    // Scan for channel c = tid: carry after samples 0..t-1.
    float mu  = mu0[tid];
    float var = var0[tid];
    const float inv = 1.0f / (float)HW;
    for (int tt = 0; tt < t; ++tt) {
        const float m  = accum_s[tt * C + tid] * inv;
        const float vt = accum_q[tt * C + tid] * inv - m * m;
        const float d  = m - mu;
        var = AFWD * var + (1.0f - AFWD) * vt + AFWD * (1.0f - AFWD) * d * d;
        mu  = mu + (1.0f - AFWD) * d;
    }

    __shared__ float smu[C];
    __shared__ float srs[C];
    smu[tid] = mu;
    srs[tid] = 1.0f / sqrtf(var + EPS);
    __syncthreads();

    const int cq = tid & 63;
    const int rs = tid >> 6;
    const float4 mu4 = ((const float4*)smu)[cq];
    const float4 rs4 = ((const float4*)srs)[cq];

    const long base = (long)(t * HW + chunk * RPC) * CQ;
    #pragma unroll 4
    for (int k = 0; k < RPC / 4; ++k) {
        const long i = base + (long)(rs + k * 4) * CQ + cq;
        const float4 v = x4[i];
        float4 o;
        o.x = (v.x - mu4.x) * rs4.x;
        o.y = (v.y - mu4.y) * rs4.y;
        o.z = (v.z - mu4.z) * rs4.z;
        o.w = (v.w - mu4.w) * rs4.w;
        out4[i] = o;
    }
}

// ---------------------------------------------------------------------------
// Host launcher. Workspace: accum_s [B*C] floats, accum_q [B*C] floats = 64KB.
// ---------------------------------------------------------------------------
extern "C" void kernel_launch(void* const* d_in, const int* in_sizes, int n_in,
                              void* d_out, int out_size, void* d_ws, size_t ws_size,
                              hipStream_t stream) {
    const float4* x4   = (const float4*)d_in[0];
    const float*  mu0  = (const float*)d_in[1];
    const float*  var0 = (const float*)d_in[2];
    // d_in[3] (u0), d_in[4] (v0): backward-only controls, unused in fwd.
    float4* out4 = (float4*)d_out;

    float* accum_s = (float*)d_ws;
    float* accum_q = accum_s + B * C;

    // Zero the atomic accumulators (harness poisons d_ws to 0xAA each call).
    hipMemsetAsync(d_ws, 0, 2 * B * C * sizeof(float), stream);

    k1_partial<<<dim3(B * CHUNKS), 256, 0, stream>>>(x4, accum_s, accum_q);

    k2_norm<<<dim3(B * CHUNKS), 256, 0, stream>>>(x4, mu0, var0,
                                                  accum_s, accum_q, out4);
}